// Round 1
// baseline (509.197 us; speedup 1.0000x reference)
//
#include <hip/hip_runtime.h>
#include <hip/hip_bf16.h>
#include <stdint.h>

// Problem constants
#define B_   32
#define N_   480
#define DIM_ 1024
#define H_   16
#define D_   64
#define M_   (B_*N_)   // 15360
#define BH_  (B_*H_)   // 512

typedef __bf16 bf16;
typedef __bf16 bf16x4 __attribute__((ext_vector_type(4)));
typedef __bf16 bf16x8 __attribute__((ext_vector_type(8)));
typedef short  short4v __attribute__((ext_vector_type(4)));
typedef float  f32x4  __attribute__((ext_vector_type(4)));

// async global->LDS, 16B per lane; LDS dest = wave-uniform base + lane*16
__device__ __forceinline__ void gld_lds16(const void* g, void* l) {
    using GP = const __attribute__((address_space(1))) unsigned int*;
    using LP = __attribute__((address_space(3))) unsigned int*;
    __builtin_amdgcn_global_load_lds((GP)(uintptr_t)g, (LP)(unsigned int)(uintptr_t)l, 16, 0, 0);
}

// ---------------- fp32 -> bf16 converts ----------------
__global__ void cvt4(const float* __restrict__ in, bf16* __restrict__ out, int n4) {
    int i = blockIdx.x * 256 + threadIdx.x;
    if (i >= n4) return;
    float4 v = ((const float4*)in)[i];
    bf16x4 o = { (bf16)v.x, (bf16)v.y, (bf16)v.z, (bf16)v.w };
    ((bf16x4*)out)[i] = o;
}

__global__ void cvtW(const float* __restrict__ Wq, const float* __restrict__ Wk,
                     const float* __restrict__ Wv, const float* __restrict__ Wo,
                     bf16* __restrict__ Wcat, bf16* __restrict__ Wob) {
    int i = blockIdx.x * 256 + threadIdx.x;
    const float* src; bf16* dst;
    switch (blockIdx.y) {
        case 0: src = Wq; dst = Wcat;                break;
        case 1: src = Wk; dst = Wcat + DIM_*DIM_;    break;
        case 2: src = Wv; dst = Wcat + 2*DIM_*DIM_;  break;
        default: src = Wo; dst = Wob;                break;
    }
    float4 v = ((const float4*)src)[i];
    bf16x4 o = { (bf16)v.x, (bf16)v.y, (bf16)v.z, (bf16)v.w };
    ((bf16x4*)dst)[i] = o;
}

// ======== shared GEMM core: 128x128 tile, BK=64, XOR-swizzled LDS ========
// LDS layout: row r (128B = 8 chunks of 16B); logical chunk c stored at
// physical slot c^(r&7). global_load_lds writes lane->slot `lane` of an
// 8-row group, so lane fetches global chunk (lane&7)^((lane>>3)&7) of row
// (lane>>3). ds_read_b128 fragment reads then hit all 32 banks 2-way (free).
#define GEMM_PRE()                                                            \
    const int tid  = threadIdx.x;                                             \
    const int lane = tid & 63;                                                \
    const int wid  = tid >> 6;                                                \
    const int wm   = wid & 1, wn = wid >> 1;                                  \
    const int m0   = blockIdx.y * 128;                                        \
    const int n0   = blockIdx.x * 128;                                        \
    const int lm   = lane & 15, lq = lane >> 4;                               \
    const int aLane = (lane >> 3) * 1024 + (((lane & 7) ^ (lane >> 3)) & 7) * 8; \
    const bf16* Asrc = A  + (m0 + wid*32) * 1024 + aLane;                     \
    const bf16* Bsrc = Bw + (n0 + wid*32) * 1024 + aLane;                     \
    bf16* AsDst = As + (wid*32)*64;                                           \
    bf16* BsDst = Bs + (wid*32)*64;                                           \
    int rowA[4], rowB[4];                                                     \
    _Pragma("unroll") for (int m = 0; m < 4; ++m) rowA[m] = (wm*64 + m*16 + lm)*64; \
    _Pragma("unroll") for (int n = 0; n < 4; ++n) rowB[n] = (wn*64 + n*16 + lm)*64; \
    const int sw = lm & 7;                                                    \
    int phys[2];                                                              \
    phys[0] = ((lq)     ^ sw) * 8;                                            \
    phys[1] = ((4 + lq) ^ sw) * 8;

#define GEMM_KLOOP(FIRST, SECOND)                                             \
    for (int k0 = 0; k0 < 1024; k0 += 64) {                                   \
        _Pragma("unroll") for (int j = 0; j < 4; ++j) {                       \
            gld_lds16(Asrc + k0 + j*8192, AsDst + j*512);                     \
            gld_lds16(Bsrc + k0 + j*8192, BsDst + j*512);                     \
        }                                                                     \
        __syncthreads();                                                      \
        _Pragma("unroll") for (int ks = 0; ks < 2; ++ks) {                    \
            bf16x8 af[4], bfr[4];                                             \
            _Pragma("unroll") for (int m = 0; m < 4; ++m)                     \
                af[m]  = *(const bf16x8*)&As[rowA[m] + phys[ks]];             \
            _Pragma("unroll") for (int n = 0; n < 4; ++n)                     \
                bfr[n] = *(const bf16x8*)&Bs[rowB[n] + phys[ks]];             \
            _Pragma("unroll") for (int m = 0; m < 4; ++m)                     \
                _Pragma("unroll") for (int n = 0; n < 4; ++n)                 \
                    acc[m][n] = __builtin_amdgcn_mfma_f32_16x16x32_bf16(      \
                        FIRST, SECOND, acc[m][n], 0, 0, 0);                   \
        }                                                                     \
        __syncthreads();                                                      \
    }

// ---------------- QKV projection GEMM ----------------
// C[m,gn] = sum_k A[m,k]*Wcat[gn,k]; Q,K -> [bh][n][d]; V -> [bh][d][n].
// V blocks use swapped MFMA operands (compute C^T) so the transposed store
// is lane-contiguous along n.
__global__ __launch_bounds__(256) void gemm_qkv(const bf16* __restrict__ A, const bf16* __restrict__ Bw,
                                                bf16* __restrict__ Qp, bf16* __restrict__ Kp,
                                                bf16* __restrict__ Vt) {
    __shared__ bf16 As[128*64];
    __shared__ bf16 Bs[128*64];
    GEMM_PRE();
    const int part = n0 >> 10;  // 0=Q,1=K,2=V (block-uniform)
    f32x4 acc[4][4] = {};

    if (part != 2) {
        GEMM_KLOOP(af[m], bfr[n]);
        // C layout: col(gn)=lm, row(gm)=lq*4+r
        bf16* dst = (part == 0) ? Qp : Kp;
        int hh[4], dd[4];
#pragma unroll
        for (int n = 0; n < 4; ++n) {
            int rem = (n0 + wn*64 + n*16 + lm) & 1023;
            hh[n] = rem >> 6; dd[n] = rem & 63;
        }
#pragma unroll
        for (int m = 0; m < 4; ++m) {
#pragma unroll
            for (int r = 0; r < 4; ++r) {
                int gm = m0 + wm*64 + m*16 + lq*4 + r;
                int b  = gm / 480;
                int nn = gm - b*480;
#pragma unroll
                for (int n = 0; n < 4; ++n)
                    dst[((b*16 + hh[n])*480 + nn)*64 + dd[n]] = (bf16)acc[m][n][r];
            }
        }
    } else {
        GEMM_KLOOP(bfr[n], af[m]);
        // C^T layout: col(gm)=lm, row(gn)=lq*4+r -> stores contiguous in nn
#pragma unroll
        for (int m = 0; m < 4; ++m) {
            int gmBase = m0 + wm*64 + m*16;      // lane-uniform; 480%16==0 -> b uniform
            int b  = gmBase / 480;
            int nn = gmBase - b*480 + lm;
#pragma unroll
            for (int n = 0; n < 4; ++n)
#pragma unroll
                for (int r = 0; r < 4; ++r) {
                    int rem = (n0 + wn*64 + n*16 + lq*4 + r) & 1023;
                    int h = rem >> 6, d = rem & 63;
                    Vt[((b*16 + h)*64 + d)*480 + nn] = (bf16)acc[m][n][r];
                }
        }
    }
}

// ---------------- fused attention v4 ----------------
// Changes vs v3:
//  * reg-staged double-buffered K/V (T14 async split): tile kt+1's global
//    loads issue right after the post-write barrier and resolve under tile
//    kt's QK^T/softmax/PV compute; LDS writes land between the barriers.
//  * XOR-swizzled LDS, conflict-free staging writes (8 consecutive lanes
//    cover all 32 banks) and balanced fragment reads:
//      Ks [96 key][64 d]:  16B chunk (r,c) at byte r*128 + ((c^(r&7))<<4)
//      Vs [64 d][128 key]: 16B chunk (r,c) at byte r*256 + (((c&8)|((c&7)^(r&7)))<<4)
//    Vs key-dim padded to 128 chunks; tail chunks clamp the global key
//    address to 472 (valid, never read by PV which uses keys 0..95 only).
#define KT 96
#define OS_LD 72
__global__ __launch_bounds__(320) void attn(const bf16* __restrict__ Qp, const bf16* __restrict__ Kp,
                                            const bf16* __restrict__ Vt, const float* __restrict__ pe,
                                            bf16* __restrict__ O) {
    __shared__ bf16 Ks[KT*64];     // 12288 B
    __shared__ bf16 Vs[64*128];    // 16384 B
    char* KsB = (char*)Ks;
    char* VsB = (char*)Vs;
    const int tid  = threadIdx.x;
    const int lane = tid & 63, wid = tid >> 6;
    const int bh   = blockIdx.y;
    const int b    = bh >> 4, h = bh & 15;
    const int qblk = blockIdx.x * 80;
    const int lm   = lane & 15, lq = lane >> 4;
    const int qbase = bh * (N_ * 64);

    // K staging: 768 16B chunks/tile; ids tid, tid+320, tid+640 (iff tid<128)
    const bool kHas2 = tid < 128;
    int kLds[3];
#pragma unroll
    for (int i = 0; i < 3; ++i) {
        int id = tid + i*320, r = id >> 3, c = id & 7;
        kLds[i] = r*128 + ((c ^ (r & 7)) << 4);
    }
    // V staging: 1024 chunks/tile; ids tid, +320, +640, +960 (iff tid<64)
    const bool vHas3 = tid < 64;
    int vLds[4], vColB[4], vRowB[4];
#pragma unroll
    for (int i = 0; i < 4; ++i) {
        int id = tid + i*320, r = id >> 4, c = id & 15;
        vLds[i]  = r*256 + (((c & 8) | ((c & 7) ^ (r & 7))) << 4);
        vColB[i] = c * 8;                      // key offset within tile
        vRowB[i] = (bh*64 + r) * 480;          // global element row base
    }

    // Q fragments (B operand): n=q=lm, k=d
    bf16x8 qb[2];
#pragma unroll
    for (int ks = 0; ks < 2; ++ks)
        qb[ks] = *(const bf16x8*)&Qp[qbase + (qblk + wid*16 + lm)*64 + ks*32 + lq*8];
    const float* peP = pe + (qblk + wid*16 + lm)*480 + lq*4;

    // fragment LDS byte offsets (swizzle folded in)
    int kOff[2];
#pragma unroll
    for (int ks = 0; ks < 2; ++ks) kOff[ks] = ((ks*4 + lq) ^ (lm & 7)) << 4;
    int vOff[6];
#pragma unroll
    for (int mf = 0; mf < 6; ++mf) {
        int c = 2*mf + (lq >> 1);
        vOff[mf] = (((c & 8) | ((c & 7) ^ (lm & 7))) << 4) + (lq & 1)*8;
    }

    uint4 kreg[3], vreg[4];
#define LOAD_TILE(T)                                                          \
    {   const char* kg = (const char*)Kp + (size_t)(qbase + (T)*KT*64)*2;     \
        kreg[0] = *(const uint4*)(kg + tid*16);                               \
        kreg[1] = *(const uint4*)(kg + tid*16 + 5120);                        \
        if (kHas2) kreg[2] = *(const uint4*)(kg + tid*16 + 10240);            \
        _Pragma("unroll") for (int i = 0; i < 4; ++i)                         \
            if (i < 3 || vHas3) {                                             \
                int key = (T)*KT + vColB[i]; if (key > 472) key = 472;        \
                vreg[i] = *(const uint4*)((const char*)Vt + (size_t)(vRowB[i] + key)*2); \
            } }

    LOAD_TILE(0);

    f32x4 ot[4] = {};      // O^T accum: m=d (4 frags), n=q
    float lsum = 0.f;

    for (int kt = 0; kt < 5; ++kt) {
        if (kt) __syncthreads();               // prev tile's LDS readers done
        *(uint4*)(KsB + kLds[0]) = kreg[0];
        *(uint4*)(KsB + kLds[1]) = kreg[1];
        if (kHas2) *(uint4*)(KsB + kLds[2]) = kreg[2];
#pragma unroll
        for (int i = 0; i < 4; ++i)
            if (i < 3 || vHas3) *(uint4*)(VsB + vLds[i]) = vreg[i];
        __syncthreads();
        if (kt < 4) LOAD_TILE(kt + 1);         // latency hides under compute

        // S^T = K Q^T; P^T = exp(scale*S^T + pe) packed as 16x16x16 B-frags
        short4v pb[6];
#pragma unroll
        for (int mf = 0; mf < 6; ++mf) {
            f32x4 s = {};
#pragma unroll
            for (int ks = 0; ks < 2; ++ks) {
                bf16x8 ka = *(const bf16x8*)(KsB + (mf*16 + lm)*128 + kOff[ks]);
                s = __builtin_amdgcn_mfma_f32_16x16x32_bf16(ka, qb[ks], s, 0, 0, 0);
            }
            f32x4 pe4 = *(const f32x4*)(peP + kt*KT + mf*16);
            bf16x4 pv;
#pragma unroll
            for (int r = 0; r < 4; ++r) {
                float e = __expf(s[r] * 0.125f + pe4[r]);
                lsum += e;
                pv[r] = (bf16)e;
            }
            pb[mf] = __builtin_bit_cast(short4v, pv);
        }

        // O^T += V^T P^T via 16x16x16 (A = V frags from swizzled Vs rows)
#pragma unroll
        for (int df = 0; df < 4; ++df) {
            const char* vrow = VsB + (df*16 + lm)*256;
#pragma unroll
            for (int mf = 0; mf < 6; ++mf) {
                short4v va = *(const short4v*)(vrow + vOff[mf]);
                ot[df] = __builtin_amdgcn_mfma_f32_16x16x16bf16_1k(va, pb[mf], ot[df], 0, 0, 0);
            }
        }
    }
#undef LOAD_TILE

    // softmax denom across the 4 lane-groups holding q=lm
    lsum += __shfl_xor(lsum, 16);
    lsum += __shfl_xor(lsum, 32);
    float rl = 1.f / lsum;

    // transpose O^T -> O via LDS (reuse Ks region), coalesced 16B stores
    __syncthreads();
    bf16* Os = Ks;  // [80 q][OS_LD]
#pragma unroll
    for (int df = 0; df < 4; ++df)
#pragma unroll
        for (int r = 0; r < 4; ++r)
            Os[(wid*16 + lm)*OS_LD + df*16 + lq*4 + r] = (bf16)(ot[df][r] * rl);
    __syncthreads();
    for (int c = tid; c < 640; c += 320) {
        int row = c >> 3, d0 = (c & 7) * 8;
        uint4 u = *(const uint4*)&Os[row*OS_LD + d0];
        *(uint4*)&O[(b*480 + qblk + row)*1024 + h*64 + d0] = u;
    }
}

// ---------------- output projection GEMM + bias ----------------
__global__ __launch_bounds__(256) void gemm_out(const bf16* __restrict__ A, const bf16* __restrict__ Bw,
                                                const float* __restrict__ bo, float* __restrict__ out) {
    __shared__ bf16 As[128*64];
    __shared__ bf16 Bs[128*64];
    GEMM_PRE();
    f32x4 acc[4][4] = {};
    GEMM_KLOOP(af[m], bfr[n]);
#pragma unroll
    for (int m = 0; m < 4; ++m)
#pragma unroll
        for (int n = 0; n < 4; ++n)
#pragma unroll
            for (int r = 0; r < 4; ++r) {
                int gm = m0 + wm*64 + m*16 + lq*4 + r;
                int gn = n0 + wn*64 + n*16 + lm;
                out[gm*1024 + gn] = acc[m][n][r] + bo[gn];
            }
}

// ---------------- launcher ----------------
extern "C" void kernel_launch(void* const* d_in, const int* in_sizes, int n_in,
                              void* d_out, int out_size, void* d_ws, size_t ws_size,
                              hipStream_t stream) {
    const float* q  = (const float*)d_in[0];
    const float* Wq = (const float*)d_in[1];
    const float* Wk = (const float*)d_in[2];
    const float* Wv = (const float*)d_in[3];
    const float* pe = (const float*)d_in[4];
    const float* Wo = (const float*)d_in[5];
    const float* bo = (const float*)d_in[6];
    float* out = (float*)d_out;

    char* ws = (char*)d_ws;
    bf16* Abf  = (bf16*)(ws);                         // q bf16 (M x 1024); reused as attn O buffer
    bf16* Wcat = (bf16*)(ws + 31457280);              // 3072 x 1024
    bf16* Wob  = (bf16*)(ws + 31457280 + 6291456);    // 1024 x 1024
    bf16* Qp   = (bf16*)(ws + 39845888);              // [bh][n][d]
    bf16* Kp   = (bf16*)(ws + 71303168);              // [bh][n][d]
    bf16* Vt   = (bf16*)(ws + 102760448);             // [bh][d][n]

    cvt4<<<(M_*DIM_/4 + 255)/256, 256, 0, stream>>>(q, Abf, M_*DIM_/4);
    cvtW<<<dim3(DIM_*DIM_/4/256, 4), 256, 0, stream>>>(Wq, Wk, Wv, Wo, Wcat, Wob);

    gemm_qkv<<<dim3(24, 120), 256, 0, stream>>>(Abf, Wcat, Qp, Kp, Vt);
    attn<<<dim3(6, 512), 320, 0, stream>>>(Qp, Kp, Vt, pe, Abf);
    gemm_out<<<dim3(8, 120), 256, 0, stream>>>(Abf, Wob, bo, out);
}

// Round 3
// 477.610 us; speedup vs baseline: 1.0661x; 1.0661x over previous
//
#include <hip/hip_runtime.h>
#include <hip/hip_bf16.h>
#include <stdint.h>

// Problem constants
#define B_   32
#define N_   480
#define DIM_ 1024
#define H_   16
#define D_   64
#define M_   (B_*N_)   // 15360
#define BH_  (B_*H_)   // 512

typedef __bf16 bf16;
typedef __bf16 bf16x4 __attribute__((ext_vector_type(4)));
typedef __bf16 bf16x8 __attribute__((ext_vector_type(8)));
typedef short  short4v __attribute__((ext_vector_type(4)));
typedef float  f32x4  __attribute__((ext_vector_type(4)));

// async global->LDS, 16B per lane; LDS dest = wave-uniform base + lane*16
__device__ __forceinline__ void gld_lds16(const void* g, void* l) {
    using GP = const __attribute__((address_space(1))) unsigned int*;
    using LP = __attribute__((address_space(3))) unsigned int*;
    __builtin_amdgcn_global_load_lds((GP)(uintptr_t)g, (LP)(unsigned int)(uintptr_t)l, 16, 0, 0);
}

// ---------------- fp32 -> bf16 converts ----------------
__global__ void cvt4(const float* __restrict__ in, bf16* __restrict__ out, int n4) {
    int i = blockIdx.x * 256 + threadIdx.x;
    if (i >= n4) return;
    float4 v = ((const float4*)in)[i];
    bf16x4 o = { (bf16)v.x, (bf16)v.y, (bf16)v.z, (bf16)v.w };
    ((bf16x4*)out)[i] = o;
}

__global__ void cvtW(const float* __restrict__ Wq, const float* __restrict__ Wk,
                     const float* __restrict__ Wv, const float* __restrict__ Wo,
                     bf16* __restrict__ Wcat, bf16* __restrict__ Wob) {
    int i = blockIdx.x * 256 + threadIdx.x;
    const float* src; bf16* dst;
    switch (blockIdx.y) {
        case 0: src = Wq; dst = Wcat;                break;
        case 1: src = Wk; dst = Wcat + DIM_*DIM_;    break;
        case 2: src = Wv; dst = Wcat + 2*DIM_*DIM_;  break;
        default: src = Wo; dst = Wob;                break;
    }
    float4 v = ((const float4*)src)[i];
    bf16x4 o = { (bf16)v.x, (bf16)v.y, (bf16)v.z, (bf16)v.w };
    ((bf16x4*)dst)[i] = o;
}

// ======== shared GEMM core: 128x128 tile, BK=64, XOR-swizzled LDS ========
// LDS layout: row r (128B = 8 chunks of 16B); logical chunk c stored at
// physical slot c^(r&7). global_load_lds writes lane->slot `lane` of an
// 8-row group, so lane fetches global chunk (lane&7)^((lane>>3)&7) of row
// (lane>>3). ds_read_b128 fragment reads then hit all 32 banks 2-way (free).
#define GEMM_PRE()                                                            \
    const int tid  = threadIdx.x;                                             \
    const int lane = tid & 63;                                                \
    const int wid  = tid >> 6;                                                \
    const int wm   = wid & 1, wn = wid >> 1;                                  \
    const int m0   = blockIdx.y * 128;                                        \
    const int n0   = blockIdx.x * 128;                                        \
    const int lm   = lane & 15, lq = lane >> 4;                               \
    const int aLane = (lane >> 3) * 1024 + (((lane & 7) ^ (lane >> 3)) & 7) * 8; \
    const bf16* Asrc = A  + (m0 + wid*32) * 1024 + aLane;                     \
    const bf16* Bsrc = Bw + (n0 + wid*32) * 1024 + aLane;                     \
    bf16* AsDst = As + (wid*32)*64;                                           \
    bf16* BsDst = Bs + (wid*32)*64;                                           \
    int rowA[4], rowB[4];                                                     \
    _Pragma("unroll") for (int m = 0; m < 4; ++m) rowA[m] = (wm*64 + m*16 + lm)*64; \
    _Pragma("unroll") for (int n = 0; n < 4; ++n) rowB[n] = (wn*64 + n*16 + lm)*64; \
    const int sw = lm & 7;                                                    \
    int phys[2];                                                              \
    phys[0] = ((lq)     ^ sw) * 8;                                            \
    phys[1] = ((4 + lq) ^ sw) * 8;

#define GEMM_KLOOP(FIRST, SECOND)                                             \
    for (int k0 = 0; k0 < 1024; k0 += 64) {                                   \
        _Pragma("unroll") for (int j = 0; j < 4; ++j) {                       \
            gld_lds16(Asrc + k0 + j*8192, AsDst + j*512);                     \
            gld_lds16(Bsrc + k0 + j*8192, BsDst + j*512);                     \
        }                                                                     \
        __syncthreads();                                                      \
        _Pragma("unroll") for (int ks = 0; ks < 2; ++ks) {                    \
            bf16x8 af[4], bfr[4];                                             \
            _Pragma("unroll") for (int m = 0; m < 4; ++m)                     \
                af[m]  = *(const bf16x8*)&As[rowA[m] + phys[ks]];             \
            _Pragma("unroll") for (int n = 0; n < 4; ++n)                     \
                bfr[n] = *(const bf16x8*)&Bs[rowB[n] + phys[ks]];             \
            _Pragma("unroll") for (int m = 0; m < 4; ++m)                     \
                _Pragma("unroll") for (int n = 0; n < 4; ++n)                 \
                    acc[m][n] = __builtin_amdgcn_mfma_f32_16x16x32_bf16(      \
                        FIRST, SECOND, acc[m][n], 0, 0, 0);                   \
        }                                                                     \
        __syncthreads();                                                      \
    }

// ---------------- QKV projection GEMM ----------------
// C[m,gn] = sum_k A[m,k]*Wcat[gn,k]; Q,K -> [bh][n][d]; V -> [bh][d][n].
// V blocks use swapped MFMA operands (compute C^T) so the transposed store
// is lane-contiguous along n.
__global__ __launch_bounds__(256) void gemm_qkv(const bf16* __restrict__ A, const bf16* __restrict__ Bw,
                                                bf16* __restrict__ Qp, bf16* __restrict__ Kp,
                                                bf16* __restrict__ Vt) {
    __shared__ bf16 As[128*64];
    __shared__ bf16 Bs[128*64];
    GEMM_PRE();
    const int part = n0 >> 10;  // 0=Q,1=K,2=V (block-uniform)
    f32x4 acc[4][4] = {};

    if (part != 2) {
        GEMM_KLOOP(af[m], bfr[n]);
        // C layout: col(gn)=lm, row(gm)=lq*4+r
        bf16* dst = (part == 0) ? Qp : Kp;
        int hh[4], dd[4];
#pragma unroll
        for (int n = 0; n < 4; ++n) {
            int rem = (n0 + wn*64 + n*16 + lm) & 1023;
            hh[n] = rem >> 6; dd[n] = rem & 63;
        }
#pragma unroll
        for (int m = 0; m < 4; ++m) {
#pragma unroll
            for (int r = 0; r < 4; ++r) {
                int gm = m0 + wm*64 + m*16 + lq*4 + r;
                int b  = gm / 480;
                int nn = gm - b*480;
#pragma unroll
                for (int n = 0; n < 4; ++n)
                    dst[((b*16 + hh[n])*480 + nn)*64 + dd[n]] = (bf16)acc[m][n][r];
            }
        }
    } else {
        GEMM_KLOOP(bfr[n], af[m]);
        // C^T layout: col(gm)=lm, row(gn)=lq*4+r -> stores contiguous in nn
#pragma unroll
        for (int m = 0; m < 4; ++m) {
            int gmBase = m0 + wm*64 + m*16;      // lane-uniform; 480%16==0 -> b uniform
            int b  = gmBase / 480;
            int nn = gmBase - b*480 + lm;
#pragma unroll
            for (int n = 0; n < 4; ++n)
#pragma unroll
                for (int r = 0; r < 4; ++r) {
                    int rem = (n0 + wn*64 + n*16 + lq*4 + r) & 1023;
                    int h = rem >> 6, d = rem & 63;
                    Vt[((b*16 + h)*64 + d)*480 + nn] = (bf16)acc[m][n][r];
                }
        }
    }
}

// ---------------- fused attention v5 (re-run; R2 bench was an infra flake) ----------------
// v4 regression root-caused: default launch_bounds let the allocator cap at
// 64 VGPRs (8-wave occupancy heuristic) -> the 7 staging uint4s spilled to
// scratch every tile (WRITE_SIZE 30MB -> 406MB). Fixes:
//  * __launch_bounds__(320, 4): VGPR cap 128, ~105 live -> no spill.
//  * exact V staging (12 chunks/row, 768 total) instead of padded 16 -> cuts
//    the +61MB FETCH of padding; clamp no longer needed (last read ends at
//    key 480 exactly).
// Structure (unchanged from v4): reg-staged double-buffer (T14), XOR-swizzled
// conflict-free LDS:
//   Ks [96 key][64 d]:  16B chunk (r,c) at byte r*128 + ((c^(r&7))<<4)
//   Vs [64 d][128 key]: 16B chunk (r,c) at byte r*256 + (((c&8)|((c&7)^(r&7)))<<4)
#define KT 96
#define OS_LD 72
__global__ __launch_bounds__(320, 4) void attn(const bf16* __restrict__ Qp, const bf16* __restrict__ Kp,
                                               const bf16* __restrict__ Vt, const float* __restrict__ pe,
                                               bf16* __restrict__ O) {
    __shared__ bf16 Ks[KT*64];     // 12288 B
    __shared__ bf16 Vs[64*128];    // 16384 B
    char* KsB = (char*)Ks;
    char* VsB = (char*)Vs;
    const int tid  = threadIdx.x;
    const int lane = tid & 63, wid = tid >> 6;
    const int bh   = blockIdx.y;
    const int b    = bh >> 4, h = bh & 15;
    const int qblk = blockIdx.x * 80;
    const int lm   = lane & 15, lq = lane >> 4;
    const int qbase = bh * (N_ * 64);

    // K staging: 768 16B chunks/tile; ids tid, tid+320, tid+640 (iff tid<128)
    const bool has2 = tid < 128;
    int kLds[3];
#pragma unroll
    for (int i = 0; i < 3; ++i) {
        int id = tid + i*320, r = id >> 3, c = id & 7;
        kLds[i] = r*128 + ((c ^ (r & 7)) << 4);
    }
    // V staging: 768 chunks/tile (64 rows x 12 chunks); same id split
    int vLds[3], vGE[3];     // LDS byte dest; global element offset (add kt*96)
#pragma unroll
    for (int i = 0; i < 3; ++i) {
        int id = tid + i*320, r = id / 12, c = id - r*12;
        vLds[i] = r*256 + (((c & 8) | ((c & 7) ^ (r & 7))) << 4);
        vGE[i]  = (bh*64 + r)*480 + c*8;   // c*8 <= 88; last 16B read ends at key 480
    }

    // Q fragments (B operand): n=q=lm, k=d
    bf16x8 qb[2];
#pragma unroll
    for (int ks = 0; ks < 2; ++ks)
        qb[ks] = *(const bf16x8*)&Qp[qbase + (qblk + wid*16 + lm)*64 + ks*32 + lq*8];
    const float* peP = pe + (qblk + wid*16 + lm)*480 + lq*4;

    // fragment LDS byte offsets (swizzle folded in)
    int kOff[2];
#pragma unroll
    for (int ks = 0; ks < 2; ++ks) kOff[ks] = ((ks*4 + lq) ^ (lm & 7)) << 4;
    int vOff[6];
#pragma unroll
    for (int mf = 0; mf < 6; ++mf) {
        int c = 2*mf + (lq >> 1);
        vOff[mf] = (((c & 8) | ((c & 7) ^ (lm & 7))) << 4) + (lq & 1)*8;
    }

    uint4 kreg[3], vreg[3];
#define LOAD_TILE(T)                                                          \
    {   const char* kg = (const char*)Kp + (size_t)(qbase + (T)*KT*64)*2;     \
        kreg[0] = *(const uint4*)(kg + tid*16);                               \
        kreg[1] = *(const uint4*)(kg + tid*16 + 5120);                        \
        if (has2) kreg[2] = *(const uint4*)(kg + tid*16 + 10240);             \
        vreg[0] = *(const uint4*)((const char*)Vt + (size_t)(vGE[0] + (T)*KT)*2); \
        vreg[1] = *(const uint4*)((const char*)Vt + (size_t)(vGE[1] + (T)*KT)*2); \
        if (has2) vreg[2] = *(const uint4*)((const char*)Vt + (size_t)(vGE[2] + (T)*KT)*2); }

    LOAD_TILE(0);

    f32x4 ot[4] = {};      // O^T accum: m=d (4 frags), n=q
    float lsum = 0.f;

    for (int kt = 0; kt < 5; ++kt) {
        if (kt) __syncthreads();               // prev tile's LDS readers done
        *(uint4*)(KsB + kLds[0]) = kreg[0];
        *(uint4*)(KsB + kLds[1]) = kreg[1];
        if (has2) *(uint4*)(KsB + kLds[2]) = kreg[2];
        *(uint4*)(VsB + vLds[0]) = vreg[0];
        *(uint4*)(VsB + vLds[1]) = vreg[1];
        if (has2) *(uint4*)(VsB + vLds[2]) = vreg[2];
        __syncthreads();
        if (kt < 4) LOAD_TILE(kt + 1);         // latency hides under compute

        // S^T = K Q^T; P^T = exp(scale*S^T + pe) packed as 16x16x16 B-frags
        short4v pb[6];
#pragma unroll
        for (int mf = 0; mf < 6; ++mf) {
            f32x4 s = {};
#pragma unroll
            for (int ks = 0; ks < 2; ++ks) {
                bf16x8 ka = *(const bf16x8*)(KsB + (mf*16 + lm)*128 + kOff[ks]);
                s = __builtin_amdgcn_mfma_f32_16x16x32_bf16(ka, qb[ks], s, 0, 0, 0);
            }
            f32x4 pe4 = *(const f32x4*)(peP + kt*KT + mf*16);
            bf16x4 pv;
#pragma unroll
            for (int r = 0; r < 4; ++r) {
                float e = __expf(s[r] * 0.125f + pe4[r]);
                lsum += e;
                pv[r] = (bf16)e;
            }
            pb[mf] = __builtin_bit_cast(short4v, pv);
        }

        // O^T += V^T P^T via 16x16x16 (A = V frags from swizzled Vs rows)
#pragma unroll
        for (int df = 0; df < 4; ++df) {
            const char* vrow = VsB + (df*16 + lm)*256;
#pragma unroll
            for (int mf = 0; mf < 6; ++mf) {
                short4v va = *(const short4v*)(vrow + vOff[mf]);
                ot[df] = __builtin_amdgcn_mfma_f32_16x16x16bf16_1k(va, pb[mf], ot[df], 0, 0, 0);
            }
        }
    }
#undef LOAD_TILE

    // softmax denom across the 4 lane-groups holding q=lm
    lsum += __shfl_xor(lsum, 16);
    lsum += __shfl_xor(lsum, 32);
    float rl = 1.f / lsum;

    // transpose O^T -> O via LDS (reuse Ks region), coalesced 16B stores
    __syncthreads();
    bf16* Os = Ks;  // [80 q][OS_LD]
#pragma unroll
    for (int df = 0; df < 4; ++df)
#pragma unroll
        for (int r = 0; r < 4; ++r)
            Os[(wid*16 + lm)*OS_LD + df*16 + lq*4 + r] = (bf16)(ot[df][r] * rl);
    __syncthreads();
    for (int c = tid; c < 640; c += 320) {
        int row = c >> 3, d0 = (c & 7) * 8;
        uint4 u = *(const uint4*)&Os[row*OS_LD + d0];
        *(uint4*)&O[(b*480 + qblk + row)*1024 + h*64 + d0] = u;
    }
}

// ---------------- output projection GEMM + bias ----------------
__global__ __launch_bounds__(256) void gemm_out(const bf16* __restrict__ A, const bf16* __restrict__ Bw,
                                                const float* __restrict__ bo, float* __restrict__ out) {
    __shared__ bf16 As[128*64];
    __shared__ bf16 Bs[128*64];
    GEMM_PRE();
    f32x4 acc[4][4] = {};
    GEMM_KLOOP(af[m], bfr[n]);
#pragma unroll
    for (int m = 0; m < 4; ++m)
#pragma unroll
        for (int n = 0; n < 4; ++n)
#pragma unroll
            for (int r = 0; r < 4; ++r) {
                int gm = m0 + wm*64 + m*16 + lq*4 + r;
                int gn = n0 + wn*64 + n*16 + lm;
                out[gm*1024 + gn] = acc[m][n][r] + bo[gn];
            }
}

// ---------------- launcher ----------------
extern "C" void kernel_launch(void* const* d_in, const int* in_sizes, int n_in,
                              void* d_out, int out_size, void* d_ws, size_t ws_size,
                              hipStream_t stream) {
    const float* q  = (const float*)d_in[0];
    const float* Wq = (const float*)d_in[1];
    const float* Wk = (const float*)d_in[2];
    const float* Wv = (const float*)d_in[3];
    const float* pe = (const float*)d_in[4];
    const float* Wo = (const float*)d_in[5];
    const float* bo = (const float*)d_in[6];
    float* out = (float*)d_out;

    char* ws = (char*)d_ws;
    bf16* Abf  = (bf16*)(ws);                         // q bf16 (M x 1024); reused as attn O buffer
    bf16* Wcat = (bf16*)(ws + 31457280);              // 3072 x 1024
    bf16* Wob  = (bf16*)(ws + 31457280 + 6291456);    // 1024 x 1024
    bf16* Qp   = (bf16*)(ws + 39845888);              // [bh][n][d]
    bf16* Kp   = (bf16*)(ws + 71303168);              // [bh][n][d]
    bf16* Vt   = (bf16*)(ws + 102760448);             // [bh][d][n]

    cvt4<<<(M_*DIM_/4 + 255)/256, 256, 0, stream>>>(q, Abf, M_*DIM_/4);
    cvtW<<<dim3(DIM_*DIM_/4/256, 4), 256, 0, stream>>>(Wq, Wk, Wv, Wo, Wcat, Wob);

    gemm_qkv<<<dim3(24, 120), 256, 0, stream>>>(Abf, Wcat, Qp, Kp, Vt);
    attn<<<dim3(6, 512), 320, 0, stream>>>(Qp, Kp, Vt, pe, Abf);
    gemm_out<<<dim3(8, 120), 256, 0, stream>>>(Abf, Wob, bo, out);
}

// Round 4
// 417.751 us; speedup vs baseline: 1.2189x; 1.1433x over previous
//
#include <hip/hip_runtime.h>
#include <hip/hip_bf16.h>
#include <stdint.h>

// Problem constants
#define B_   32
#define N_   480
#define DIM_ 1024
#define H_   16
#define D_   64
#define M_   (B_*N_)   // 15360
#define BH_  (B_*H_)   // 512

typedef __bf16 bf16;
typedef __bf16 bf16x4 __attribute__((ext_vector_type(4)));
typedef __bf16 bf16x8 __attribute__((ext_vector_type(8)));
typedef short  short4v __attribute__((ext_vector_type(4)));
typedef float  f32x4  __attribute__((ext_vector_type(4)));

// async global->LDS, 16B per lane; LDS dest = wave-uniform base + lane*16
__device__ __forceinline__ void gld_lds16(const void* g, void* l) {
    using GP = const __attribute__((address_space(1))) unsigned int*;
    using LP = __attribute__((address_space(3))) unsigned int*;
    __builtin_amdgcn_global_load_lds((GP)(uintptr_t)g, (LP)(unsigned int)(uintptr_t)l, 16, 0, 0);
}

// ---------------- fp32 -> bf16 converts ----------------
__global__ void cvt4(const float* __restrict__ in, bf16* __restrict__ out, int n4) {
    int i = blockIdx.x * 256 + threadIdx.x;
    if (i >= n4) return;
    float4 v = ((const float4*)in)[i];
    bf16x4 o = { (bf16)v.x, (bf16)v.y, (bf16)v.z, (bf16)v.w };
    ((bf16x4*)out)[i] = o;
}

__global__ void cvtW(const float* __restrict__ Wq, const float* __restrict__ Wk,
                     const float* __restrict__ Wv, const float* __restrict__ Wo,
                     bf16* __restrict__ Wcat, bf16* __restrict__ Wob) {
    int i = blockIdx.x * 256 + threadIdx.x;
    const float* src; bf16* dst;
    switch (blockIdx.y) {
        case 0: src = Wq; dst = Wcat;                break;
        case 1: src = Wk; dst = Wcat + DIM_*DIM_;    break;
        case 2: src = Wv; dst = Wcat + 2*DIM_*DIM_;  break;
        default: src = Wo; dst = Wob;                break;
    }
    float4 v = ((const float4*)src)[i];
    bf16x4 o = { (bf16)v.x, (bf16)v.y, (bf16)v.z, (bf16)v.w };
    ((bf16x4*)dst)[i] = o;
}

// ======== shared GEMM core: 128x128 tile, BK=64, XOR-swizzled LDS ========
// LDS layout: row r (128B = 8 chunks of 16B); logical chunk c stored at
// physical slot c^(r&7). global_load_lds writes lane->slot `lane` of an
// 8-row group, so lane fetches global chunk (lane&7)^((lane>>3)&7) of row
// (lane>>3). ds_read_b128 fragment reads then hit all 32 banks 2-way (free).
#define GEMM_PRE()                                                            \
    const int tid  = threadIdx.x;                                             \
    const int lane = tid & 63;                                                \
    const int wid  = tid >> 6;                                                \
    const int wm   = wid & 1, wn = wid >> 1;                                  \
    const int m0   = blockIdx.y * 128;                                        \
    const int n0   = blockIdx.x * 128;                                        \
    const int lm   = lane & 15, lq = lane >> 4;                               \
    const int aLane = (lane >> 3) * 1024 + (((lane & 7) ^ (lane >> 3)) & 7) * 8; \
    const bf16* Asrc = A  + (m0 + wid*32) * 1024 + aLane;                     \
    const bf16* Bsrc = Bw + (n0 + wid*32) * 1024 + aLane;                     \
    bf16* AsDst = As + (wid*32)*64;                                           \
    bf16* BsDst = Bs + (wid*32)*64;                                           \
    int rowA[4], rowB[4];                                                     \
    _Pragma("unroll") for (int m = 0; m < 4; ++m) rowA[m] = (wm*64 + m*16 + lm)*64; \
    _Pragma("unroll") for (int n = 0; n < 4; ++n) rowB[n] = (wn*64 + n*16 + lm)*64; \
    const int sw = lm & 7;                                                    \
    int phys[2];                                                              \
    phys[0] = ((lq)     ^ sw) * 8;                                            \
    phys[1] = ((4 + lq) ^ sw) * 8;

#define GEMM_KLOOP(FIRST, SECOND)                                             \
    for (int k0 = 0; k0 < 1024; k0 += 64) {                                   \
        _Pragma("unroll") for (int j = 0; j < 4; ++j) {                       \
            gld_lds16(Asrc + k0 + j*8192, AsDst + j*512);                     \
            gld_lds16(Bsrc + k0 + j*8192, BsDst + j*512);                     \
        }                                                                     \
        __syncthreads();                                                      \
        _Pragma("unroll") for (int ks = 0; ks < 2; ++ks) {                    \
            bf16x8 af[4], bfr[4];                                             \
            _Pragma("unroll") for (int m = 0; m < 4; ++m)                     \
                af[m]  = *(const bf16x8*)&As[rowA[m] + phys[ks]];             \
            _Pragma("unroll") for (int n = 0; n < 4; ++n)                     \
                bfr[n] = *(const bf16x8*)&Bs[rowB[n] + phys[ks]];             \
            _Pragma("unroll") for (int m = 0; m < 4; ++m)                     \
                _Pragma("unroll") for (int n = 0; n < 4; ++n)                 \
                    acc[m][n] = __builtin_amdgcn_mfma_f32_16x16x32_bf16(      \
                        FIRST, SECOND, acc[m][n], 0, 0, 0);                   \
        }                                                                     \
        __syncthreads();                                                      \
    }

// ---------------- QKV projection GEMM ----------------
// C[m,gn] = sum_k A[m,k]*Wcat[gn,k]; Q,K -> [bh][n][d]; V -> [bh][d][n].
// V blocks use swapped MFMA operands (compute C^T) so the transposed store
// is lane-contiguous along n.
__global__ __launch_bounds__(256) void gemm_qkv(const bf16* __restrict__ A, const bf16* __restrict__ Bw,
                                                bf16* __restrict__ Qp, bf16* __restrict__ Kp,
                                                bf16* __restrict__ Vt) {
    __shared__ bf16 As[128*64];
    __shared__ bf16 Bs[128*64];
    GEMM_PRE();
    const int part = n0 >> 10;  // 0=Q,1=K,2=V (block-uniform)
    f32x4 acc[4][4] = {};

    if (part != 2) {
        GEMM_KLOOP(af[m], bfr[n]);
        // C layout: col(gn)=lm, row(gm)=lq*4+r
        bf16* dst = (part == 0) ? Qp : Kp;
        int hh[4], dd[4];
#pragma unroll
        for (int n = 0; n < 4; ++n) {
            int rem = (n0 + wn*64 + n*16 + lm) & 1023;
            hh[n] = rem >> 6; dd[n] = rem & 63;
        }
#pragma unroll
        for (int m = 0; m < 4; ++m) {
#pragma unroll
            for (int r = 0; r < 4; ++r) {
                int gm = m0 + wm*64 + m*16 + lq*4 + r;
                int b  = gm / 480;
                int nn = gm - b*480;
#pragma unroll
                for (int n = 0; n < 4; ++n)
                    dst[((b*16 + hh[n])*480 + nn)*64 + dd[n]] = (bf16)acc[m][n][r];
            }
        }
    } else {
        GEMM_KLOOP(bfr[n], af[m]);
        // C^T layout: col(gm)=lm, row(gn)=lq*4+r -> stores contiguous in nn
#pragma unroll
        for (int m = 0; m < 4; ++m) {
            int gmBase = m0 + wm*64 + m*16;      // lane-uniform; 480%16==0 -> b uniform
            int b  = gmBase / 480;
            int nn = gmBase - b*480 + lm;
#pragma unroll
            for (int n = 0; n < 4; ++n)
#pragma unroll
                for (int r = 0; r < 4; ++r) {
                    int rem = (n0 + wn*64 + n*16 + lq*4 + r) & 1023;
                    int h = rem >> 6, d = rem & 63;
                    Vt[((b*16 + h)*64 + d)*480 + nn] = (bf16)acc[m][n][r];
                }
        }
    }
}

// ---------------- fused attention v6 ----------------
// v5 post-mortem: launch_bounds didn't lift the 64-VGPR budget (LDS-derived
// occupancy heuristic wins); reg-staging spilled ~290MB to scratch. v6
// removes the register pressure structurally: async global_load_lds staging
// (zero staging regs, same pre-swizzled-source pattern as the GEMM core),
// double-buffered LDS, ONE barrier per tile.
//  * 6 waves x 16 q = 96 q-rows/block, grid (5, 512).
//  * K tile: 768 chunks = 2 DMA instr/wave. LDS chunk (r,c) at r*128+((c^(r&7))<<4),
//    linear in chunk id -> lane fetches global chunk (lane&7)^(r&7) of row r.
//  * V tile: rows padded to 16 chunks (256B); pad sources clamp to chunk 11
//    (L2-duplicate, ~no extra HBM; pad slots have logical c>=12, never read
//    by PV which uses c<=11). 1024 chunks = 16 DMA windows over 6 waves.
//  * Per iter: barrier (drains tile-kt DMA, issued a full compute phase ago)
//    -> pe loads (issued BEFORE DMAs so in-order vmcnt retirement of pe never
//    forces a DMA drain) -> issue tile kt+1 into buf^1 -> compute buf.
//    Race-free: buf^1's readers (compute kt-1) all passed the barrier.
#define KT 96
#define OS_LD 72
__global__ __launch_bounds__(384, 3) void attn(const bf16* __restrict__ Qp, const bf16* __restrict__ Kp,
                                               const bf16* __restrict__ Vt, const float* __restrict__ pe,
                                               bf16* __restrict__ O) {
    __shared__ bf16 Ks[2][KT*64];    // 2 x 12288 B
    __shared__ bf16 Vs[2][64*128];   // 2 x 16384 B
    const int tid  = threadIdx.x;
    const int lane = tid & 63, wid = tid >> 6;   // 6 waves
    const int bh   = blockIdx.y;
    const int b    = bh >> 4, h = bh & 15;
    const int qblk = blockIdx.x * 96;
    const int lm   = lane & 15, lq = lane >> 4;
    const int qbase = bh * (N_ * 64);

    // K staging: per-lane global element offset within a window (row=lane>>3,
    // fetched chunk = (lane&7)^(lane>>3); window j adds j*512 elems / j*1024 B LDS)
    const int kROff = (lane >> 3)*64 + ((lane & 7) ^ (lane >> 3))*8;
    // V staging: window j = wid + 6*i; row r = j*4 + (lane>>4), phys chunk p = lane&15,
    // logical chunk c = (p&8)|((p&7)^(r&7)), clamped to 11 for pad slots.
    int vOffG[3];
#pragma unroll
    for (int i = 0; i < 3; ++i) {
        int j = wid + 6*i;
        int r = j*4 + (lane >> 4);
        int p = lane & 15;
        int c = (p & 8) | ((p & 7) ^ (r & 7));
        if (c > 11) c = 11;
        vOffG[i] = (bh*64 + r)*480 + c*8;
    }

    // Q fragments (B operand): n=q=lm, k=d
    bf16x8 qb[2];
#pragma unroll
    for (int ks = 0; ks < 2; ++ks)
        qb[ks] = *(const bf16x8*)&Qp[qbase + (qblk + wid*16 + lm)*64 + ks*32 + lq*8];
    const float* peP = pe + (qblk + wid*16 + lm)*480 + lq*4;

    // fragment LDS byte offsets (swizzle folded in)
    int kOff[2];
#pragma unroll
    for (int ks = 0; ks < 2; ++ks) kOff[ks] = ((ks*4 + lq) ^ (lm & 7)) << 4;
    int vOff[6];
#pragma unroll
    for (int mf = 0; mf < 6; ++mf) {
        int c = 2*mf + (lq >> 1);
        vOff[mf] = (((c & 8) | ((c & 7) ^ (lm & 7))) << 4) + (lq & 1)*8;
    }

#define STAGE(T, BUF)                                                         \
    {   const bf16* kg = Kp + qbase + (T)*(KT*64);                            \
        char* kd = (char*)Ks[BUF];                                            \
        gld_lds16(kg + (wid*2 + 0)*512 + kROff, kd + (wid*2 + 0)*1024);       \
        gld_lds16(kg + (wid*2 + 1)*512 + kROff, kd + (wid*2 + 1)*1024);       \
        char* vd = (char*)Vs[BUF];                                            \
        _Pragma("unroll") for (int i = 0; i < 3; ++i) {                       \
            int j = wid + 6*i;                                                \
            if (j < 16) gld_lds16(Vt + vOffG[i] + (T)*KT, vd + j*1024);       \
        } }

    STAGE(0, 0);

    f32x4 ot[4] = {};      // O^T accum: m=d (4 frags), n=q
    float lsum = 0.f;

    for (int kt = 0; kt < 5; ++kt) {
        const int cur = kt & 1;
        __syncthreads();                       // drains tile-kt DMA (issued a full phase ago)
        // pe loads first (older than DMAs in vmcnt order -> their waits can't drain DMAs)
        f32x4 pe4[6];
#pragma unroll
        for (int mf = 0; mf < 6; ++mf)
            pe4[mf] = *(const f32x4*)(peP + kt*KT + mf*16);
        if (kt < 4) STAGE(kt + 1, cur ^ 1);    // latency hides under compute
        const char* KsB = (const char*)Ks[cur];
        const char* VsB = (const char*)Vs[cur];

        // S^T = K Q^T; P^T = exp(scale*S^T + pe) packed as 16x16x16 B-frags
        short4v pb[6];
#pragma unroll
        for (int mf = 0; mf < 6; ++mf) {
            f32x4 s = {};
#pragma unroll
            for (int ks = 0; ks < 2; ++ks) {
                bf16x8 ka = *(const bf16x8*)(KsB + (mf*16 + lm)*128 + kOff[ks]);
                s = __builtin_amdgcn_mfma_f32_16x16x32_bf16(ka, qb[ks], s, 0, 0, 0);
            }
            bf16x4 pv;
#pragma unroll
            for (int r = 0; r < 4; ++r) {
                float e = __expf(s[r] * 0.125f + pe4[mf][r]);
                lsum += e;
                pv[r] = (bf16)e;
            }
            pb[mf] = __builtin_bit_cast(short4v, pv);
        }

        // O^T += V^T P^T via 16x16x16 (A = V frags from swizzled Vs rows)
#pragma unroll
        for (int df = 0; df < 4; ++df) {
            const char* vrow = VsB + (df*16 + lm)*256;
#pragma unroll
            for (int mf = 0; mf < 6; ++mf) {
                short4v va = *(const short4v*)(vrow + vOff[mf]);
                ot[df] = __builtin_amdgcn_mfma_f32_16x16x16bf16_1k(va, pb[mf], ot[df], 0, 0, 0);
            }
        }
    }
#undef STAGE

    // softmax denom across the 4 lane-groups holding q=lm
    lsum += __shfl_xor(lsum, 16);
    lsum += __shfl_xor(lsum, 32);
    float rl = 1.f / lsum;

    // transpose O^T -> O via LDS (reuse Ks region: 96*72*2 = 13.8KB <= 24.6KB)
    __syncthreads();
    bf16* Os = &Ks[0][0];  // [96 q][OS_LD]
#pragma unroll
    for (int df = 0; df < 4; ++df)
#pragma unroll
        for (int r = 0; r < 4; ++r)
            Os[(wid*16 + lm)*OS_LD + df*16 + lq*4 + r] = (bf16)(ot[df][r] * rl);
    __syncthreads();
    for (int c = tid; c < 768; c += 384) {
        int row = c >> 3, d0 = (c & 7) * 8;
        uint4 u = *(const uint4*)&Os[row*OS_LD + d0];
        *(uint4*)&O[(b*480 + qblk + row)*1024 + h*64 + d0] = u;
    }
}

// ---------------- output projection GEMM + bias ----------------
__global__ __launch_bounds__(256) void gemm_out(const bf16* __restrict__ A, const bf16* __restrict__ Bw,
                                                const float* __restrict__ bo, float* __restrict__ out) {
    __shared__ bf16 As[128*64];
    __shared__ bf16 Bs[128*64];
    GEMM_PRE();
    f32x4 acc[4][4] = {};
    GEMM_KLOOP(af[m], bfr[n]);
#pragma unroll
    for (int m = 0; m < 4; ++m)
#pragma unroll
        for (int n = 0; n < 4; ++n)
#pragma unroll
            for (int r = 0; r < 4; ++r) {
                int gm = m0 + wm*64 + m*16 + lq*4 + r;
                int gn = n0 + wn*64 + n*16 + lm;
                out[gm*1024 + gn] = acc[m][n][r] + bo[gn];
            }
}

// ---------------- launcher ----------------
extern "C" void kernel_launch(void* const* d_in, const int* in_sizes, int n_in,
                              void* d_out, int out_size, void* d_ws, size_t ws_size,
                              hipStream_t stream) {
    const float* q  = (const float*)d_in[0];
    const float* Wq = (const float*)d_in[1];
    const float* Wk = (const float*)d_in[2];
    const float* Wv = (const float*)d_in[3];
    const float* pe = (const float*)d_in[4];
    const float* Wo = (const float*)d_in[5];
    const float* bo = (const float*)d_in[6];
    float* out = (float*)d_out;

    char* ws = (char*)d_ws;
    bf16* Abf  = (bf16*)(ws);                         // q bf16 (M x 1024); reused as attn O buffer
    bf16* Wcat = (bf16*)(ws + 31457280);              // 3072 x 1024
    bf16* Wob  = (bf16*)(ws + 31457280 + 6291456);    // 1024 x 1024
    bf16* Qp   = (bf16*)(ws + 39845888);              // [bh][n][d]
    bf16* Kp   = (bf16*)(ws + 71303168);              // [bh][n][d]
    bf16* Vt   = (bf16*)(ws + 102760448);             // [bh][d][n]

    cvt4<<<(M_*DIM_/4 + 255)/256, 256, 0, stream>>>(q, Abf, M_*DIM_/4);
    cvtW<<<dim3(DIM_*DIM_/4/256, 4), 256, 0, stream>>>(Wq, Wk, Wv, Wo, Wcat, Wob);

    gemm_qkv<<<dim3(24, 120), 256, 0, stream>>>(Abf, Wcat, Qp, Kp, Vt);
    attn<<<dim3(5, 512), 384, 0, stream>>>(Qp, Kp, Vt, pe, Abf);
    gemm_out<<<dim3(8, 120), 256, 0, stream>>>(Abf, Wob, bo, out);
}